// Round 6
// baseline (467.640 us; speedup 1.0000x reference)
//
#include <hip/hip_runtime.h>

// GCN link predictor. fp32 math, bf16 intermediates + bf16 MFMA GEMM.
// Pipeline: CSR build (hist -> hierarchical scan -> bucketed fill) ->
//           [MFMA GEMM+dinv-scale -> gather-agg]x2 -> pair-dot decode.
// norm factorization: h'[i] = dinv[i]*(x@W)[i];  z[i] = dinv[i]*(h'[i] + sum_{src->i} h'[src]) + b.
// R3: gathers half-wave float4 (90->59us). R4: bf16 intermediates (agg 59->~35us).
// R5: GEMM on matrix cores (55->~10us each). R6: fill was 47us @ 51.5MB writes (= E x 64B:
// random 4B scatter -> full-line writeback). Two-phase bucket fill: stage packed records into
// contiguous per-bucket segments (dense lines), then per-bucket LDS-cursor scatter.

typedef __attribute__((ext_vector_type(8))) short short8;   // 8 bf16 (A/B frag)
typedef __attribute__((ext_vector_type(4))) float floatx4;  // C/D frag

__device__ __forceinline__ unsigned short f2bf(float f) {
    union { float f; unsigned int u; } v; v.f = f;
    unsigned int u = v.u;
    u += 0x7fffu + ((u >> 16) & 1u);   // round-to-nearest-even
    return (unsigned short)(u >> 16);
}

__device__ __forceinline__ unsigned int pack2(float a, float b) {
    return (unsigned int)f2bf(a) | ((unsigned int)f2bf(b) << 16);
}

__device__ __forceinline__ float4 cvt4(uint2 u) {
    float4 f;
    f.x = __uint_as_float(u.x << 16);
    f.y = __uint_as_float(u.x & 0xffff0000u);
    f.z = __uint_as_float(u.y << 16);
    f.w = __uint_as_float(u.y & 0xffff0000u);
    return f;
}

__global__ __launch_bounds__(256) void zero_i32(int* __restrict__ p, int n) {
    int i = blockIdx.x * blockDim.x + threadIdx.x;
    if (i < n) p[i] = 0;
}

__global__ __launch_bounds__(256) void hist_kernel(const int* __restrict__ dst,
                                                   int* __restrict__ counts, int E) {
    int e = blockIdx.x * blockDim.x + threadIdx.x;
    if (e < E) atomicAdd(&counts[dst[e]], 1);
}

// --- hierarchical exclusive scan over counts[N] ---

__global__ __launch_bounds__(256) void scan_block_sums(const int* __restrict__ counts,
                                                       int* __restrict__ blk_sums, int N) {
    __shared__ int s[256];
    int t = threadIdx.x;
    int i = blockIdx.x * 256 + t;
    s[t] = (i < N) ? counts[i] : 0;
    __syncthreads();
#pragma unroll
    for (int off = 128; off > 0; off >>= 1) {
        if (t < off) s[t] += s[t + off];
        __syncthreads();
    }
    if (t == 0) blk_sums[blockIdx.x] = s[0];
}

__global__ __launch_bounds__(256) void scan_offsets(int* __restrict__ blk_sums, int B) {
    __shared__ int s[2][256];
    int t = threadIdx.x;
    int v = (t < B) ? blk_sums[t] : 0;
    int cur = 0;
    s[0][t] = v;
    __syncthreads();
#pragma unroll
    for (int off = 1; off < 256; off <<= 1) {
        int nxt = cur ^ 1;
        int val = s[cur][t];
        if (t >= off) val += s[cur][t - off];
        s[nxt][t] = val;
        __syncthreads();
        cur = nxt;
    }
    if (t < B) blk_sums[t] = s[cur][t] - v;  // exclusive
}

__global__ __launch_bounds__(256) void scan_final(const int* __restrict__ counts,
                                                  const int* __restrict__ blk_off,
                                                  int* __restrict__ row_ptr,
                                                  float* __restrict__ dinv, int N) {
    __shared__ int s[2][256];
    int t = threadIdx.x;
    int i = blockIdx.x * 256 + t;
    int c = (i < N) ? counts[i] : 0;
    int cur = 0;
    s[0][t] = c;
    __syncthreads();
#pragma unroll
    for (int off = 1; off < 256; off <<= 1) {
        int nxt = cur ^ 1;
        int val = s[cur][t];
        if (t >= off) val += s[cur][t - off];
        s[nxt][t] = val;
        __syncthreads();
        cur = nxt;
    }
    if (i < N) {
        int inc = s[cur][t] + blk_off[blockIdx.x];
        row_ptr[i] = inc - c;
        dinv[i] = rsqrtf((float)(c + 1));  // +1 self-loop
        if (i == N - 1) row_ptr[N] = inc;
    }
}

// Phase 1: append packed (src<<6 | dst&63) into the bucket's contiguous CSR segment.
// Bucket = 64-node range; segment base = row_ptr[b<<6], exact size, no overflow possible.
__global__ __launch_bounds__(256) void bucket_stage_kernel(const int* __restrict__ src,
                                                           const int* __restrict__ dst,
                                                           const int* __restrict__ row_ptr,
                                                           int* __restrict__ bcur,
                                                           unsigned int* __restrict__ stage,
                                                           int E) {
    int e = blockIdx.x * blockDim.x + threadIdx.x;
    if (e < E) {
        int d = dst[e];
        int b = d >> 6;
        int base = row_ptr[b << 6];
        int pos = base + atomicAdd(&bcur[b], 1);
        stage[pos] = ((unsigned int)src[e] << 6) | (unsigned int)(d & 63);
    }
}

// Phase 2: one block per bucket; 64 node-cursors in LDS; writes confined to the bucket's
// ~4 KB srcs_sorted segment -> dense line fill.
__global__ __launch_bounds__(256) void bucket_scatter_kernel(const unsigned int* __restrict__ stage,
                                                             const int* __restrict__ row_ptr,
                                                             int* __restrict__ srcs_sorted,
                                                             int N) {
    __shared__ int lcur[64];
    int b = blockIdx.x;
    int lo = b << 6;
    int hi = min(lo + 64, N);
    int t = threadIdx.x;
    if (t < 64) lcur[t] = (lo + t < hi) ? row_ptr[lo + t] : 0;
    __syncthreads();
    int beg = row_ptr[lo], end = row_ptr[hi];
    for (int i = beg + t; i < end; i += 256) {
        unsigned int rec = stage[i];
        int pos = atomicAdd(&lcur[rec & 63u], 1);
        srcs_sorted[pos] = (int)(rec >> 6);
    }
}

// MFMA GEMM: H[r][c] = bf16( dinv[r] * sum_k X[r][k]*W[k][c] ), 64 rows x 128 cols per block.
// 4 waves; wave w computes rows 16w..16w+15 x all 128 cols = 8 n-tiles of 16x16x32 MFMA.
template <bool BF16IN>
__global__ __launch_bounds__(256) void gemm_mfma_kernel(const void* __restrict__ Xv,
                                                        const float* __restrict__ W,
                                                        const float* __restrict__ dinv,
                                                        uint2* __restrict__ H, int N) {
    __shared__ __align__(16) char smem[50176];
    short* WB = (short*)smem;            // [nt][kt][lane][j]
    short* XL = (short*)(smem + 32768);  // [row][k], row stride 136 shorts
    float* Cst = (float*)smem;           // epilogue overlap: [row][col], stride 132 floats

    const int tid = threadIdx.x;
    const int w = tid >> 6;
    const int lane = tid & 63;
    const int blk = blockIdx.x;

    // --- stage W (128x128 fp32) -> WB (bf16 B-frag layout) ---
    {
        const float4* W4 = (const float4*)W;
#pragma unroll
        for (int i = 0; i < 16; ++i) {
            int f = tid + i * 256;
            int k = f >> 5;
            int c4 = f & 31;
            float4 wv = W4[f];
            int kt = k >> 5, q = (k >> 3) & 3, j = k & 7;
            float e[4] = {wv.x, wv.y, wv.z, wv.w};
#pragma unroll
            for (int m = 0; m < 4; ++m) {
                int c = c4 * 4 + m;
                int nt = c >> 4;
                int ln = q * 16 + (c & 15);
                WB[((nt * 4 + kt) * 64 + ln) * 8 + j] = (short)f2bf(e[m]);
            }
        }
    }

    // --- stage X tile (64 rows) -> XL bf16 row-major ---
    {
#pragma unroll
        for (int i = 0; i < 8; ++i) {
            int f = tid + i * 256;
            int row = f >> 5;
            int c4 = f & 31;
            int gr = min(blk * 64 + row, N - 1);
            uint2 u;
            if constexpr (BF16IN) {
                u = ((const uint2*)Xv)[(size_t)gr * 32 + c4];
            } else {
                float4 xv = ((const float4*)Xv)[(size_t)gr * 32 + c4];
                u.x = pack2(xv.x, xv.y);
                u.y = pack2(xv.z, xv.w);
            }
            *(uint2*)&XL[row * 136 + c4 * 4] = u;
        }
    }
    __syncthreads();

    // --- MFMA main ---
    const int arow = w * 16 + (lane & 15);
    const int koff = (lane >> 4) * 8;
    short8 a[4];
#pragma unroll
    for (int kt = 0; kt < 4; ++kt)
        a[kt] = *(const short8*)&XL[arow * 136 + kt * 32 + koff];

    floatx4 acc[8];
#pragma unroll
    for (int nt = 0; nt < 8; ++nt) acc[nt] = (floatx4){0.f, 0.f, 0.f, 0.f};

#pragma unroll
    for (int kt = 0; kt < 4; ++kt) {
#pragma unroll
        for (int nt = 0; nt < 8; ++nt) {
            short8 b = *(const short8*)&WB[((nt * 4 + kt) * 64 + lane) * 8];
            acc[nt] = __builtin_amdgcn_mfma_f32_16x16x32_bf16(a[kt], b, acc[nt], 0, 0, 0);
        }
    }
    __syncthreads();

    // --- epilogue: C frags -> LDS fp32 -> scale+pack -> coalesced stores ---
    {
        int q = lane >> 4, cn = lane & 15;
#pragma unroll
        for (int nt = 0; nt < 8; ++nt)
#pragma unroll
            for (int r = 0; r < 4; ++r)
                Cst[(w * 16 + q * 4 + r) * 132 + nt * 16 + cn] = acc[nt][r];
    }
    __syncthreads();
    {
#pragma unroll
        for (int i = 0; i < 8; ++i) {
            int f = tid + i * 256;
            int row = f >> 5;
            int c4 = f & 31;
            int gr = blk * 64 + row;
            if (gr < N) {
                float4 v = *(float4*)&Cst[row * 132 + c4 * 4];
                float di = dinv[gr];
                uint2 o;
                o.x = pack2(v.x * di, v.y * di);
                o.y = pack2(v.z * di, v.w * di);
                H[(size_t)gr * 32 + c4] = o;
            }
        }
    }
}

// Half-wave (32 lanes) per node; lane holds 4 cols as bf16x4 (uint2) -> one 256 B row
// per half-wave. fp32 accumulate. Edge loop unrolled 4x, 2 accumulators.
__global__ __launch_bounds__(256) void agg_kernel(const unsigned short* __restrict__ Hp,
                                                  const int* __restrict__ row_ptr,
                                                  const int* __restrict__ srcs,
                                                  const float* __restrict__ dinv,
                                                  const float* __restrict__ bias,
                                                  unsigned short* __restrict__ Z,
                                                  int N, int do_relu) {
    int gw = (int)((blockIdx.x * blockDim.x + threadIdx.x) >> 6);  // wave id
    int lane = threadIdx.x & 63;
    int half = lane >> 5;
    int hl = lane & 31;
    int n = gw * 2 + half;
    if (n >= N) return;

    const uint2* H2 = (const uint2*)Hp;
    float4 acc = cvt4(H2[(size_t)n * 32 + hl]);  // self-loop term
    float4 acc2 = make_float4(0.f, 0.f, 0.f, 0.f);

    int j = row_ptr[n], end = row_ptr[n + 1];
    for (; j + 3 < end; j += 4) {
        int s0 = srcs[j], s1 = srcs[j + 1], s2 = srcs[j + 2], s3 = srcs[j + 3];
        float4 t0 = cvt4(H2[(size_t)s0 * 32 + hl]);
        float4 t1 = cvt4(H2[(size_t)s1 * 32 + hl]);
        float4 t2 = cvt4(H2[(size_t)s2 * 32 + hl]);
        float4 t3 = cvt4(H2[(size_t)s3 * 32 + hl]);
        acc.x += t0.x; acc.y += t0.y; acc.z += t0.z; acc.w += t0.w;
        acc2.x += t1.x; acc2.y += t1.y; acc2.z += t1.z; acc2.w += t1.w;
        acc.x += t2.x; acc.y += t2.y; acc.z += t2.z; acc.w += t2.w;
        acc2.x += t3.x; acc2.y += t3.y; acc2.z += t3.z; acc2.w += t3.w;
    }
    for (; j < end; ++j) {
        int s = srcs[j];
        float4 t = cvt4(H2[(size_t)s * 32 + hl]);
        acc.x += t.x; acc.y += t.y; acc.z += t.z; acc.w += t.w;
    }
    acc.x += acc2.x; acc.y += acc2.y; acc.z += acc2.z; acc.w += acc2.w;

    float di = dinv[n];
    float4 bv = ((const float4*)bias)[hl];
    float ox = di * acc.x + bv.x;
    float oy = di * acc.y + bv.y;
    float oz = di * acc.z + bv.z;
    float ow = di * acc.w + bv.w;
    if (do_relu) {
        ox = fmaxf(ox, 0.f); oy = fmaxf(oy, 0.f);
        oz = fmaxf(oz, 0.f); ow = fmaxf(ow, 0.f);
    }
    uint2 o;
    o.x = pack2(ox, oy);
    o.y = pack2(oz, ow);
    ((uint2*)Z)[(size_t)n * 32 + hl] = o;
}

// Half-wave per pair: out[p] = dot(z2[a], z2[b]); lane holds 4 cols (bf16x4).
__global__ __launch_bounds__(256) void decode_kernel(const unsigned short* __restrict__ Z,
                                                     const int* __restrict__ pa,
                                                     const int* __restrict__ pb,
                                                     float* __restrict__ out, int P) {
    int gw = (int)((blockIdx.x * blockDim.x + threadIdx.x) >> 6);
    int lane = threadIdx.x & 63;
    int half = lane >> 5;
    int hl = lane & 31;
    int p = gw * 2 + half;
    if (p >= P) return;
    int a = pa[p], b = pb[p];
    const uint2* Z2 = (const uint2*)Z;
    float4 va = cvt4(Z2[(size_t)a * 32 + hl]);
    float4 vb = cvt4(Z2[(size_t)b * 32 + hl]);
    float v = va.x * vb.x + va.y * vb.y + va.z * vb.z + va.w * vb.w;
#pragma unroll
    for (int off = 16; off > 0; off >>= 1) v += __shfl_down(v, off, 32);
    if (hl == 0) out[p] = v;
}

extern "C" void kernel_launch(void* const* d_in, const int* in_sizes, int n_in,
                              void* d_out, int out_size, void* d_ws, size_t ws_size,
                              hipStream_t stream) {
    const int*   edge_index = (const int*)d_in[0];
    const int*   edge_pairs = (const int*)d_in[1];
    const float* emb        = (const float*)d_in[2];
    const float* W1         = (const float*)d_in[3];
    const float* b1         = (const float*)d_in[4];
    const float* W2         = (const float*)d_in[5];
    const float* b2         = (const float*)d_in[6];
    float* out = (float*)d_out;

    int E = in_sizes[0] / 2;
    int P = in_sizes[1] / 2;
    int N = in_sizes[2] / 128;
    int B = (N + 255) / 256;   // scan blocks (196 for N=50000, must be <= 256)
    int K = (N + 63) / 64;     // buckets (782)

    const int* src = edge_index;
    const int* dst = edge_index + E;
    const int* pa  = edge_pairs;
    const int* pb  = edge_pairs + P;

    char* ws = (char*)d_ws;
    size_t off = 0;
    auto alloc = [&](size_t bytes) -> void* {
        void* p = ws + off;
        off = (off + bytes + 255) & ~(size_t)255;
        return p;
    };
    unsigned short* bufA = (unsigned short*)alloc((size_t)N * 128 * 2); // h' (bf16)
    unsigned short* bufB = (unsigned short*)alloc((size_t)N * 128 * 2); // z  (bf16)
    int*   srcs_sorted = (int*)alloc((size_t)E * sizeof(int));
    unsigned int* stage = (unsigned int*)alloc((size_t)E * sizeof(unsigned int));
    int*   row_ptr     = (int*)alloc((size_t)(N + 1) * sizeof(int));
    int*   counts      = (int*)alloc((size_t)(N + K) * sizeof(int));    // counts[N] + bcur[K]
    int*   bcur        = counts + N;
    float* dinv        = (float*)alloc((size_t)N * sizeof(float));
    int*   blk_sums    = (int*)alloc((size_t)B * sizeof(int));

    // CSR build
    zero_i32<<<(N + K + 255) / 256, 256, 0, stream>>>(counts, N + K);
    hist_kernel<<<(E + 255) / 256, 256, 0, stream>>>(dst, counts, E);
    scan_block_sums<<<B, 256, 0, stream>>>(counts, blk_sums, N);
    scan_offsets<<<1, 256, 0, stream>>>(blk_sums, B);
    scan_final<<<B, 256, 0, stream>>>(counts, blk_sums, row_ptr, dinv, N);
    bucket_stage_kernel<<<(E + 255) / 256, 256, 0, stream>>>(src, dst, row_ptr, bcur, stage, E);
    bucket_scatter_kernel<<<K, 256, 0, stream>>>(stage, row_ptr, srcs_sorted, N);

    // Layer 1: h1' = dinv*(emb@W1) -> agg+b1+relu -> z1 (bufB)
    gemm_mfma_kernel<false><<<(N + 63) / 64, 256, 0, stream>>>(emb, W1, dinv, (uint2*)bufA, N);
    agg_kernel<<<(N + 7) / 8, 256, 0, stream>>>(bufA, row_ptr, srcs_sorted, dinv, b1, bufB, N, 1);

    // Layer 2: h2' = dinv*(z1@W2) -> agg+b2 -> z2 (bufB)
    gemm_mfma_kernel<true><<<(N + 63) / 64, 256, 0, stream>>>(bufB, W2, dinv, (uint2*)bufA, N);
    agg_kernel<<<(N + 7) / 8, 256, 0, stream>>>(bufA, row_ptr, srcs_sorted, dinv, b2, bufB, N, 0);

    // Decode
    decode_kernel<<<(P + 7) / 8, 256, 0, stream>>>(bufB, pa, pb, out, P);
}

// Round 7
// 268.184 us; speedup vs baseline: 1.7437x; 1.7437x over previous
//
#include <hip/hip_runtime.h>

// GCN link predictor. fp32 math, bf16 intermediates + bf16 MFMA GEMM.
// Pipeline: CSR build (block-hist -> bucket scans -> stage -> scatter[+row_ptr,dinv]) ->
//           [MFMA GEMM+dinv-scale -> gather-agg]x2 -> pair-dot decode.
// norm factorization: h'[i] = dinv[i]*(x@W)[i];  z[i] = dinv[i]*(h'[i] + sum_{src->i} h'[src]) + b.
// R3: gathers half-wave float4. R4: bf16 intermediates. R5: MFMA GEMM (55->~10us each).
// R6 FAILED: 800k global atomics on 782 bucket counters = 240ns/atomic chain = 190us.
// R7: deterministic per-(block,bucket) offsets via hist+scan (NO hot global atomics; LDS
// atomics only), bucket-confined writes for line density; node hist/scan folded into scatter.

typedef __attribute__((ext_vector_type(8))) short short8;   // 8 bf16 (A/B frag)
typedef __attribute__((ext_vector_type(4))) float floatx4;  // C/D frag

#define STAGE_G 128   // staging blocks; records/block/bucket ~ E/(G*NB) ~ 8 (32 B sub-range)

__device__ __forceinline__ unsigned short f2bf(float f) {
    union { float f; unsigned int u; } v; v.f = f;
    unsigned int u = v.u;
    u += 0x7fffu + ((u >> 16) & 1u);   // round-to-nearest-even
    return (unsigned short)(u >> 16);
}

__device__ __forceinline__ unsigned int pack2(float a, float b) {
    return (unsigned int)f2bf(a) | ((unsigned int)f2bf(b) << 16);
}

__device__ __forceinline__ float4 cvt4(uint2 u) {
    float4 f;
    f.x = __uint_as_float(u.x << 16);
    f.y = __uint_as_float(u.x & 0xffff0000u);
    f.z = __uint_as_float(u.y << 16);
    f.w = __uint_as_float(u.y & 0xffff0000u);
    return f;
}

// --- CSR build ---

// Per-block bucket histogram (LDS atomics only). bhist layout block-major: bhist[g*NB+b].
__global__ __launch_bounds__(256) void block_hist_kernel(const int* __restrict__ dst,
                                                         int* __restrict__ bhist,
                                                         int E, int NB) {
    __shared__ int bh[1024];
    int t = threadIdx.x, g = blockIdx.x;
    for (int b = t; b < NB; b += 256) bh[b] = 0;
    __syncthreads();
    int chunk = (E + gridDim.x - 1) / gridDim.x;
    int lo = g * chunk, hi = min(lo + chunk, E);
    for (int i = lo + t; i < hi; i += 256) atomicAdd(&bh[dst[i] >> 6], 1);
    __syncthreads();
    for (int b = t; b < NB; b += 256) bhist[g * NB + b] = bh[b];
}

// Per-bucket scan over the G=128 blocks: bhist[g][b] -> exclusive prefix (in place); T[b]=total.
__global__ __launch_bounds__(128) void s1_scan_blocks(int* __restrict__ bhist,
                                                      int* __restrict__ T, int NB) {
    __shared__ int s[2][128];
    int b = blockIdx.x, t = threadIdx.x;
    int v = bhist[t * NB + b];
    int cur = 0;
    s[0][t] = v;
    __syncthreads();
#pragma unroll
    for (int off = 1; off < 128; off <<= 1) {
        int nxt = cur ^ 1;
        int val = s[cur][t];
        if (t >= off) val += s[cur][t - off];
        s[nxt][t] = val;
        __syncthreads();
        cur = nxt;
    }
    int inc = s[cur][t];
    bhist[t * NB + b] = inc - v;       // exclusive over blocks
    if (t == 127) T[b] = inc;
}

// Exclusive scan of bucket totals T[NB] -> bucket_base[NB+1] (one block).
__global__ __launch_bounds__(256) void s2_scan_buckets(const int* __restrict__ T,
                                                       int* __restrict__ bucket_base, int NB) {
    __shared__ int sums[256];
    int t = threadIdx.x;
    int chunk = (NB + 255) >> 8;
    int lo = t * chunk, hi = min(lo + chunk, NB);
    int s = 0;
    for (int i = lo; i < hi; ++i) s += T[i];
    sums[t] = s;
    __syncthreads();
    if (t == 0) {
        int run = 0;
        for (int i = 0; i < 256; ++i) { int v = sums[i]; sums[i] = run; run += v; }
    }
    __syncthreads();
    int run = sums[t];
    for (int i = lo; i < hi; ++i) { bucket_base[i] = run; run += T[i]; }
    if (lo < NB && hi == NB) bucket_base[NB] = run;   // == E
}

// Stage: each block writes its records into its own deterministic sub-range of each
// bucket segment (LDS cursors; no global atomics). rec = src<<6 | (dst&63).
__global__ __launch_bounds__(256) void stage_kernel(const int* __restrict__ src,
                                                    const int* __restrict__ dst,
                                                    const int* __restrict__ bhist,
                                                    const int* __restrict__ bucket_base,
                                                    unsigned int* __restrict__ stage,
                                                    int E, int NB) {
    __shared__ int lcur[1024];
    int t = threadIdx.x, g = blockIdx.x;
    for (int b = t; b < NB; b += 256) lcur[b] = bucket_base[b] + bhist[g * NB + b];
    __syncthreads();
    int chunk = (E + gridDim.x - 1) / gridDim.x;
    int lo = g * chunk, hi = min(lo + chunk, E);
    for (int i = lo + t; i < hi; i += 256) {
        int d = dst[i];
        int pos = atomicAdd(&lcur[d >> 6], 1);
        stage[pos] = ((unsigned int)src[i] << 6) | (unsigned int)(d & 63);
    }
}

// Scatter: one block per bucket. Pass 1 counts 64 node degrees (LDS); wave-scan emits
// row_ptr + dinv; pass 2 scatters srcs into the bucket's dense ~4 KB segment.
__global__ __launch_bounds__(256) void scatter_kernel(const unsigned int* __restrict__ stage,
                                                      const int* __restrict__ bucket_base,
                                                      int* __restrict__ row_ptr,
                                                      float* __restrict__ dinv,
                                                      int* __restrict__ srcs_sorted,
                                                      int N) {
    __shared__ int cnt[64];
    __shared__ int lcur[64];
    int b = blockIdx.x, t = threadIdx.x;
    int lo = b << 6;
    int base = bucket_base[b], basen = bucket_base[b + 1];
    if (t < 64) cnt[t] = 0;
    __syncthreads();
    for (int i = base + t; i < basen; i += 256) atomicAdd(&cnt[stage[i] & 63u], 1);
    __syncthreads();
    if (t < 64) {
        int v = cnt[t];
        int inc = v;
#pragma unroll
        for (int off = 1; off < 64; off <<= 1) {
            int x = __shfl_up(inc, off, 64);
            if (t >= off) inc += x;
        }
        int exc = inc - v;
        int node = lo + t;
        if (node < N) {
            row_ptr[node] = base + exc;
            dinv[node] = rsqrtf((float)(v + 1));   // +1 self-loop
            if (node == N - 1) row_ptr[N] = base + exc + v;
        }
        lcur[t] = base + exc;
    }
    __syncthreads();
    for (int i = base + t; i < basen; i += 256) {
        unsigned int rec = stage[i];
        int pos = atomicAdd(&lcur[rec & 63u], 1);
        srcs_sorted[pos] = (int)(rec >> 6);
    }
}

// --- MFMA GEMM: H[r][c] = bf16( dinv[r] * sum_k X[r][k]*W[k][c] ), 64x128 per block ---
template <bool BF16IN>
__global__ __launch_bounds__(256) void gemm_mfma_kernel(const void* __restrict__ Xv,
                                                        const float* __restrict__ W,
                                                        const float* __restrict__ dinv,
                                                        uint2* __restrict__ H, int N) {
    __shared__ __align__(16) char smem[50176];
    short* WB = (short*)smem;            // [nt][kt][lane][j]
    short* XL = (short*)(smem + 32768);  // [row][k], row stride 136 shorts
    float* Cst = (float*)smem;           // epilogue overlap: [row][col], stride 132 floats

    const int tid = threadIdx.x;
    const int w = tid >> 6;
    const int lane = tid & 63;
    const int blk = blockIdx.x;

    {
        const float4* W4 = (const float4*)W;
#pragma unroll
        for (int i = 0; i < 16; ++i) {
            int f = tid + i * 256;
            int k = f >> 5;
            int c4 = f & 31;
            float4 wv = W4[f];
            int kt = k >> 5, q = (k >> 3) & 3, j = k & 7;
            float e[4] = {wv.x, wv.y, wv.z, wv.w};
#pragma unroll
            for (int m = 0; m < 4; ++m) {
                int c = c4 * 4 + m;
                int nt = c >> 4;
                int ln = q * 16 + (c & 15);
                WB[((nt * 4 + kt) * 64 + ln) * 8 + j] = (short)f2bf(e[m]);
            }
        }
    }
    {
#pragma unroll
        for (int i = 0; i < 8; ++i) {
            int f = tid + i * 256;
            int row = f >> 5;
            int c4 = f & 31;
            int gr = min(blk * 64 + row, N - 1);
            uint2 u;
            if constexpr (BF16IN) {
                u = ((const uint2*)Xv)[(size_t)gr * 32 + c4];
            } else {
                float4 xv = ((const float4*)Xv)[(size_t)gr * 32 + c4];
                u.x = pack2(xv.x, xv.y);
                u.y = pack2(xv.z, xv.w);
            }
            *(uint2*)&XL[row * 136 + c4 * 4] = u;
        }
    }
    __syncthreads();

    const int arow = w * 16 + (lane & 15);
    const int koff = (lane >> 4) * 8;
    short8 a[4];
#pragma unroll
    for (int kt = 0; kt < 4; ++kt)
        a[kt] = *(const short8*)&XL[arow * 136 + kt * 32 + koff];

    floatx4 acc[8];
#pragma unroll
    for (int nt = 0; nt < 8; ++nt) acc[nt] = (floatx4){0.f, 0.f, 0.f, 0.f};

#pragma unroll
    for (int kt = 0; kt < 4; ++kt) {
#pragma unroll
        for (int nt = 0; nt < 8; ++nt) {
            short8 b = *(const short8*)&WB[((nt * 4 + kt) * 64 + lane) * 8];
            acc[nt] = __builtin_amdgcn_mfma_f32_16x16x32_bf16(a[kt], b, acc[nt], 0, 0, 0);
        }
    }
    __syncthreads();

    {
        int q = lane >> 4, cn = lane & 15;
#pragma unroll
        for (int nt = 0; nt < 8; ++nt)
#pragma unroll
            for (int r = 0; r < 4; ++r)
                Cst[(w * 16 + q * 4 + r) * 132 + nt * 16 + cn] = acc[nt][r];
    }
    __syncthreads();
    {
#pragma unroll
        for (int i = 0; i < 8; ++i) {
            int f = tid + i * 256;
            int row = f >> 5;
            int c4 = f & 31;
            int gr = blk * 64 + row;
            if (gr < N) {
                float4 v = *(float4*)&Cst[row * 132 + c4 * 4];
                float di = dinv[gr];
                uint2 o;
                o.x = pack2(v.x * di, v.y * di);
                o.y = pack2(v.z * di, v.w * di);
                H[(size_t)gr * 32 + c4] = o;
            }
        }
    }
}

// Half-wave (32 lanes) per node; lane holds 4 cols as bf16x4 (uint2). fp32 accumulate.
__global__ __launch_bounds__(256) void agg_kernel(const unsigned short* __restrict__ Hp,
                                                  const int* __restrict__ row_ptr,
                                                  const int* __restrict__ srcs,
                                                  const float* __restrict__ dinv,
                                                  const float* __restrict__ bias,
                                                  unsigned short* __restrict__ Z,
                                                  int N, int do_relu) {
    int gw = (int)((blockIdx.x * blockDim.x + threadIdx.x) >> 6);
    int lane = threadIdx.x & 63;
    int half = lane >> 5;
    int hl = lane & 31;
    int n = gw * 2 + half;
    if (n >= N) return;

    const uint2* H2 = (const uint2*)Hp;
    float4 acc = cvt4(H2[(size_t)n * 32 + hl]);  // self-loop term
    float4 acc2 = make_float4(0.f, 0.f, 0.f, 0.f);

    int j = row_ptr[n], end = row_ptr[n + 1];
    for (; j + 3 < end; j += 4) {
        int s0 = srcs[j], s1 = srcs[j + 1], s2 = srcs[j + 2], s3 = srcs[j + 3];
        float4 t0 = cvt4(H2[(size_t)s0 * 32 + hl]);
        float4 t1 = cvt4(H2[(size_t)s1 * 32 + hl]);
        float4 t2 = cvt4(H2[(size_t)s2 * 32 + hl]);
        float4 t3 = cvt4(H2[(size_t)s3 * 32 + hl]);
        acc.x += t0.x; acc.y += t0.y; acc.z += t0.z; acc.w += t0.w;
        acc2.x += t1.x; acc2.y += t1.y; acc2.z += t1.z; acc2.w += t1.w;
        acc.x += t2.x; acc.y += t2.y; acc.z += t2.z; acc.w += t2.w;
        acc2.x += t3.x; acc2.y += t3.y; acc2.z += t3.z; acc2.w += t3.w;
    }
    for (; j < end; ++j) {
        int s = srcs[j];
        float4 t = cvt4(H2[(size_t)s * 32 + hl]);
        acc.x += t.x; acc.y += t.y; acc.z += t.z; acc.w += t.w;
    }
    acc.x += acc2.x; acc.y += acc2.y; acc.z += acc2.z; acc.w += acc2.w;

    float di = dinv[n];
    float4 bv = ((const float4*)bias)[hl];
    float ox = di * acc.x + bv.x;
    float oy = di * acc.y + bv.y;
    float oz = di * acc.z + bv.z;
    float ow = di * acc.w + bv.w;
    if (do_relu) {
        ox = fmaxf(ox, 0.f); oy = fmaxf(oy, 0.f);
        oz = fmaxf(oz, 0.f); ow = fmaxf(ow, 0.f);
    }
    uint2 o;
    o.x = pack2(ox, oy);
    o.y = pack2(oz, ow);
    ((uint2*)Z)[(size_t)n * 32 + hl] = o;
}

// Half-wave per pair: out[p] = dot(z2[a], z2[b]); lane holds 4 cols (bf16x4).
__global__ __launch_bounds__(256) void decode_kernel(const unsigned short* __restrict__ Z,
                                                     const int* __restrict__ pa,
                                                     const int* __restrict__ pb,
                                                     float* __restrict__ out, int P) {
    int gw = (int)((blockIdx.x * blockDim.x + threadIdx.x) >> 6);
    int lane = threadIdx.x & 63;
    int half = lane >> 5;
    int hl = lane & 31;
    int p = gw * 2 + half;
    if (p >= P) return;
    int a = pa[p], b = pb[p];
    const uint2* Z2 = (const uint2*)Z;
    float4 va = cvt4(Z2[(size_t)a * 32 + hl]);
    float4 vb = cvt4(Z2[(size_t)b * 32 + hl]);
    float v = va.x * vb.x + va.y * vb.y + va.z * vb.z + va.w * vb.w;
#pragma unroll
    for (int off = 16; off > 0; off >>= 1) v += __shfl_down(v, off, 32);
    if (hl == 0) out[p] = v;
}

extern "C" void kernel_launch(void* const* d_in, const int* in_sizes, int n_in,
                              void* d_out, int out_size, void* d_ws, size_t ws_size,
                              hipStream_t stream) {
    const int*   edge_index = (const int*)d_in[0];
    const int*   edge_pairs = (const int*)d_in[1];
    const float* emb        = (const float*)d_in[2];
    const float* W1         = (const float*)d_in[3];
    const float* b1         = (const float*)d_in[4];
    const float* W2         = (const float*)d_in[5];
    const float* b2         = (const float*)d_in[6];
    float* out = (float*)d_out;

    int E = in_sizes[0] / 2;
    int P = in_sizes[1] / 2;
    int N = in_sizes[2] / 128;
    int NB = (N + 63) / 64;    // buckets (782 for N=50000; must be <= 1024)

    const int* src = edge_index;
    const int* dst = edge_index + E;
    const int* pa  = edge_pairs;
    const int* pb  = edge_pairs + P;

    char* ws = (char*)d_ws;
    size_t off = 0;
    auto alloc = [&](size_t bytes) -> void* {
        void* p = ws + off;
        off = (off + bytes + 255) & ~(size_t)255;
        return p;
    };
    unsigned short* bufA = (unsigned short*)alloc((size_t)N * 128 * 2); // h' (bf16)
    unsigned short* bufB = (unsigned short*)alloc((size_t)N * 128 * 2); // z  (bf16)
    int*   srcs_sorted  = (int*)alloc((size_t)E * sizeof(int));
    unsigned int* stage = (unsigned int*)alloc((size_t)E * sizeof(unsigned int));
    int*   row_ptr      = (int*)alloc((size_t)(N + 1) * sizeof(int));
    float* dinv         = (float*)alloc((size_t)N * sizeof(float));
    int*   bhist        = (int*)alloc((size_t)STAGE_G * NB * sizeof(int));
    int*   T            = (int*)alloc((size_t)NB * sizeof(int));
    int*   bucket_base  = (int*)alloc((size_t)(NB + 1) * sizeof(int));

    // CSR build — no hot global atomics anywhere.
    block_hist_kernel<<<STAGE_G, 256, 0, stream>>>(dst, bhist, E, NB);
    s1_scan_blocks<<<NB, 128, 0, stream>>>(bhist, T, NB);
    s2_scan_buckets<<<1, 256, 0, stream>>>(T, bucket_base, NB);
    stage_kernel<<<STAGE_G, 256, 0, stream>>>(src, dst, bhist, bucket_base, stage, E, NB);
    scatter_kernel<<<NB, 256, 0, stream>>>(stage, bucket_base, row_ptr, dinv, srcs_sorted, N);

    // Layer 1: h1' = dinv*(emb@W1) -> agg+b1+relu -> z1 (bufB)
    gemm_mfma_kernel<false><<<(N + 63) / 64, 256, 0, stream>>>(emb, W1, dinv, (uint2*)bufA, N);
    agg_kernel<<<(N + 7) / 8, 256, 0, stream>>>(bufA, row_ptr, srcs_sorted, dinv, b1, bufB, N, 1);

    // Layer 2: h2' = dinv*(z1@W2) -> agg+b2 -> z2 (bufB)
    gemm_mfma_kernel<true><<<(N + 63) / 64, 256, 0, stream>>>(bufB, W2, dinv, (uint2*)bufA, N);
    agg_kernel<<<(N + 7) / 8, 256, 0, stream>>>(bufA, row_ptr, srcs_sorted, dinv, b2, bufB, N, 0);

    // Decode
    decode_kernel<<<(P + 7) / 8, 256, 0, stream>>>(bufB, pa, pb, out, P);
}

// Round 8
// 248.281 us; speedup vs baseline: 1.8835x; 1.0802x over previous
//
#include <hip/hip_runtime.h>

// GCN link predictor. fp32 math, bf16 intermediates + bf16 MFMA GEMM.
// Pipeline: CSR build (block-hist -> bucket scans -> stage -> scatter[+row_ptr,dinv]) ->
//           [MFMA GEMM+dinv-scale -> gather-agg]x2 -> pair-dot decode.
// norm factorization: h'[i] = dinv[i]*(x@W)[i];  z[i] = dinv[i]*(h'[i] + sum_{src->i} h'[src]) + b.
// R3: gathers half-wave float4. R4: bf16 intermediates. R5: MFMA GEMM (55->~10us each).
// R6 FAILED: hot global atomics on 782 counters (190us). R7: deterministic-offset bucket CSR
// (no hot global atomics), ~26us total. R8: decode gets the R3 treatment -- 4 pairs per
// half-wave (8 row-gathers in flight, interleaved shfl chains, float4 stores); agg unroll 4->8.

typedef __attribute__((ext_vector_type(8))) short short8;   // 8 bf16 (A/B frag)
typedef __attribute__((ext_vector_type(4))) float floatx4;  // C/D frag

#define STAGE_G 128   // staging blocks; records/block/bucket ~ E/(G*NB) ~ 8 (32 B sub-range)

__device__ __forceinline__ unsigned short f2bf(float f) {
    union { float f; unsigned int u; } v; v.f = f;
    unsigned int u = v.u;
    u += 0x7fffu + ((u >> 16) & 1u);   // round-to-nearest-even
    return (unsigned short)(u >> 16);
}

__device__ __forceinline__ unsigned int pack2(float a, float b) {
    return (unsigned int)f2bf(a) | ((unsigned int)f2bf(b) << 16);
}

__device__ __forceinline__ float4 cvt4(uint2 u) {
    float4 f;
    f.x = __uint_as_float(u.x << 16);
    f.y = __uint_as_float(u.x & 0xffff0000u);
    f.z = __uint_as_float(u.y << 16);
    f.w = __uint_as_float(u.y & 0xffff0000u);
    return f;
}

// --- CSR build ---

__global__ __launch_bounds__(256) void block_hist_kernel(const int* __restrict__ dst,
                                                         int* __restrict__ bhist,
                                                         int E, int NB) {
    __shared__ int bh[1024];
    int t = threadIdx.x, g = blockIdx.x;
    for (int b = t; b < NB; b += 256) bh[b] = 0;
    __syncthreads();
    int chunk = (E + gridDim.x - 1) / gridDim.x;
    int lo = g * chunk, hi = min(lo + chunk, E);
    for (int i = lo + t; i < hi; i += 256) atomicAdd(&bh[dst[i] >> 6], 1);
    __syncthreads();
    for (int b = t; b < NB; b += 256) bhist[g * NB + b] = bh[b];
}

__global__ __launch_bounds__(128) void s1_scan_blocks(int* __restrict__ bhist,
                                                      int* __restrict__ T, int NB) {
    __shared__ int s[2][128];
    int b = blockIdx.x, t = threadIdx.x;
    int v = bhist[t * NB + b];
    int cur = 0;
    s[0][t] = v;
    __syncthreads();
#pragma unroll
    for (int off = 1; off < 128; off <<= 1) {
        int nxt = cur ^ 1;
        int val = s[cur][t];
        if (t >= off) val += s[cur][t - off];
        s[nxt][t] = val;
        __syncthreads();
        cur = nxt;
    }
    int inc = s[cur][t];
    bhist[t * NB + b] = inc - v;       // exclusive over blocks
    if (t == 127) T[b] = inc;
}

__global__ __launch_bounds__(256) void s2_scan_buckets(const int* __restrict__ T,
                                                       int* __restrict__ bucket_base, int NB) {
    __shared__ int sums[256];
    int t = threadIdx.x;
    int chunk = (NB + 255) >> 8;
    int lo = t * chunk, hi = min(lo + chunk, NB);
    int s = 0;
    for (int i = lo; i < hi; ++i) s += T[i];
    sums[t] = s;
    __syncthreads();
    if (t == 0) {
        int run = 0;
        for (int i = 0; i < 256; ++i) { int v = sums[i]; sums[i] = run; run += v; }
    }
    __syncthreads();
    int run = sums[t];
    for (int i = lo; i < hi; ++i) { bucket_base[i] = run; run += T[i]; }
    if (lo < NB && hi == NB) bucket_base[NB] = run;   // == E
}

__global__ __launch_bounds__(256) void stage_kernel(const int* __restrict__ src,
                                                    const int* __restrict__ dst,
                                                    const int* __restrict__ bhist,
                                                    const int* __restrict__ bucket_base,
                                                    unsigned int* __restrict__ stage,
                                                    int E, int NB) {
    __shared__ int lcur[1024];
    int t = threadIdx.x, g = blockIdx.x;
    for (int b = t; b < NB; b += 256) lcur[b] = bucket_base[b] + bhist[g * NB + b];
    __syncthreads();
    int chunk = (E + gridDim.x - 1) / gridDim.x;
    int lo = g * chunk, hi = min(lo + chunk, E);
    for (int i = lo + t; i < hi; i += 256) {
        int d = dst[i];
        int pos = atomicAdd(&lcur[d >> 6], 1);
        stage[pos] = ((unsigned int)src[i] << 6) | (unsigned int)(d & 63);
    }
}

__global__ __launch_bounds__(256) void scatter_kernel(const unsigned int* __restrict__ stage,
                                                      const int* __restrict__ bucket_base,
                                                      int* __restrict__ row_ptr,
                                                      float* __restrict__ dinv,
                                                      int* __restrict__ srcs_sorted,
                                                      int N) {
    __shared__ int cnt[64];
    __shared__ int lcur[64];
    int b = blockIdx.x, t = threadIdx.x;
    int lo = b << 6;
    int base = bucket_base[b], basen = bucket_base[b + 1];
    if (t < 64) cnt[t] = 0;
    __syncthreads();
    for (int i = base + t; i < basen; i += 256) atomicAdd(&cnt[stage[i] & 63u], 1);
    __syncthreads();
    if (t < 64) {
        int v = cnt[t];
        int inc = v;
#pragma unroll
        for (int off = 1; off < 64; off <<= 1) {
            int x = __shfl_up(inc, off, 64);
            if (t >= off) inc += x;
        }
        int exc = inc - v;
        int node = lo + t;
        if (node < N) {
            row_ptr[node] = base + exc;
            dinv[node] = rsqrtf((float)(v + 1));   // +1 self-loop
            if (node == N - 1) row_ptr[N] = base + exc + v;
        }
        lcur[t] = base + exc;
    }
    __syncthreads();
    for (int i = base + t; i < basen; i += 256) {
        unsigned int rec = stage[i];
        int pos = atomicAdd(&lcur[rec & 63u], 1);
        srcs_sorted[pos] = (int)(rec >> 6);
    }
}

// --- MFMA GEMM: H[r][c] = bf16( dinv[r] * sum_k X[r][k]*W[k][c] ), 64x128 per block ---
template <bool BF16IN>
__global__ __launch_bounds__(256) void gemm_mfma_kernel(const void* __restrict__ Xv,
                                                        const float* __restrict__ W,
                                                        const float* __restrict__ dinv,
                                                        uint2* __restrict__ H, int N) {
    __shared__ __align__(16) char smem[50176];
    short* WB = (short*)smem;            // [nt][kt][lane][j]
    short* XL = (short*)(smem + 32768);  // [row][k], row stride 136 shorts
    float* Cst = (float*)smem;           // epilogue overlap: [row][col], stride 132 floats

    const int tid = threadIdx.x;
    const int w = tid >> 6;
    const int lane = tid & 63;
    const int blk = blockIdx.x;

    {
        const float4* W4 = (const float4*)W;
#pragma unroll
        for (int i = 0; i < 16; ++i) {
            int f = tid + i * 256;
            int k = f >> 5;
            int c4 = f & 31;
            float4 wv = W4[f];
            int kt = k >> 5, q = (k >> 3) & 3, j = k & 7;
            float e[4] = {wv.x, wv.y, wv.z, wv.w};
#pragma unroll
            for (int m = 0; m < 4; ++m) {
                int c = c4 * 4 + m;
                int nt = c >> 4;
                int ln = q * 16 + (c & 15);
                WB[((nt * 4 + kt) * 64 + ln) * 8 + j] = (short)f2bf(e[m]);
            }
        }
    }
    {
#pragma unroll
        for (int i = 0; i < 8; ++i) {
            int f = tid + i * 256;
            int row = f >> 5;
            int c4 = f & 31;
            int gr = min(blk * 64 + row, N - 1);
            uint2 u;
            if constexpr (BF16IN) {
                u = ((const uint2*)Xv)[(size_t)gr * 32 + c4];
            } else {
                float4 xv = ((const float4*)Xv)[(size_t)gr * 32 + c4];
                u.x = pack2(xv.x, xv.y);
                u.y = pack2(xv.z, xv.w);
            }
            *(uint2*)&XL[row * 136 + c4 * 4] = u;
        }
    }
    __syncthreads();

    const int arow = w * 16 + (lane & 15);
    const int koff = (lane >> 4) * 8;
    short8 a[4];
#pragma unroll
    for (int kt = 0; kt < 4; ++kt)
        a[kt] = *(const short8*)&XL[arow * 136 + kt * 32 + koff];

    floatx4 acc[8];
#pragma unroll
    for (int nt = 0; nt < 8; ++nt) acc[nt] = (floatx4){0.f, 0.f, 0.f, 0.f};

#pragma unroll
    for (int kt = 0; kt < 4; ++kt) {
#pragma unroll
        for (int nt = 0; nt < 8; ++nt) {
            short8 b = *(const short8*)&WB[((nt * 4 + kt) * 64 + lane) * 8];
            acc[nt] = __builtin_amdgcn_mfma_f32_16x16x32_bf16(a[kt], b, acc[nt], 0, 0, 0);
        }
    }
    __syncthreads();

    {
        int q = lane >> 4, cn = lane & 15;
#pragma unroll
        for (int nt = 0; nt < 8; ++nt)
#pragma unroll
            for (int r = 0; r < 4; ++r)
                Cst[(w * 16 + q * 4 + r) * 132 + nt * 16 + cn] = acc[nt][r];
    }
    __syncthreads();
    {
#pragma unroll
        for (int i = 0; i < 8; ++i) {
            int f = tid + i * 256;
            int row = f >> 5;
            int c4 = f & 31;
            int gr = blk * 64 + row;
            if (gr < N) {
                float4 v = *(float4*)&Cst[row * 132 + c4 * 4];
                float di = dinv[gr];
                uint2 o;
                o.x = pack2(v.x * di, v.y * di);
                o.y = pack2(v.z * di, v.w * di);
                H[(size_t)gr * 32 + c4] = o;
            }
        }
    }
}

// Half-wave (32 lanes) per node; lane holds 4 cols as bf16x4 (uint2). fp32 accumulate.
// Edge loop: unroll-8 (4 accs) -> unroll-4 -> scalar tail.
__global__ __launch_bounds__(256) void agg_kernel(const unsigned short* __restrict__ Hp,
                                                  const int* __restrict__ row_ptr,
                                                  const int* __restrict__ srcs,
                                                  const float* __restrict__ dinv,
                                                  const float* __restrict__ bias,
                                                  unsigned short* __restrict__ Z,
                                                  int N, int do_relu) {
    int gw = (int)((blockIdx.x * blockDim.x + threadIdx.x) >> 6);
    int lane = threadIdx.x & 63;
    int half = lane >> 5;
    int hl = lane & 31;
    int n = gw * 2 + half;
    if (n >= N) return;

    const uint2* H2 = (const uint2*)Hp;
    float4 a0 = cvt4(H2[(size_t)n * 32 + hl]);  // self-loop term
    float4 a1 = make_float4(0.f, 0.f, 0.f, 0.f);
    float4 a2 = make_float4(0.f, 0.f, 0.f, 0.f);
    float4 a3 = make_float4(0.f, 0.f, 0.f, 0.f);

    int j = row_ptr[n], end = row_ptr[n + 1];
    for (; j + 7 < end; j += 8) {
        uint2 u0 = H2[(size_t)srcs[j + 0] * 32 + hl];
        uint2 u1 = H2[(size_t)srcs[j + 1] * 32 + hl];
        uint2 u2 = H2[(size_t)srcs[j + 2] * 32 + hl];
        uint2 u3 = H2[(size_t)srcs[j + 3] * 32 + hl];
        uint2 u4 = H2[(size_t)srcs[j + 4] * 32 + hl];
        uint2 u5 = H2[(size_t)srcs[j + 5] * 32 + hl];
        uint2 u6 = H2[(size_t)srcs[j + 6] * 32 + hl];
        uint2 u7 = H2[(size_t)srcs[j + 7] * 32 + hl];
        float4 t;
        t = cvt4(u0); a0.x += t.x; a0.y += t.y; a0.z += t.z; a0.w += t.w;
        t = cvt4(u1); a1.x += t.x; a1.y += t.y; a1.z += t.z; a1.w += t.w;
        t = cvt4(u2); a2.x += t.x; a2.y += t.y; a2.z += t.z; a2.w += t.w;
        t = cvt4(u3); a3.x += t.x; a3.y += t.y; a3.z += t.z; a3.w += t.w;
        t = cvt4(u4); a0.x += t.x; a0.y += t.y; a0.z += t.z; a0.w += t.w;
        t = cvt4(u5); a1.x += t.x; a1.y += t.y; a1.z += t.z; a1.w += t.w;
        t = cvt4(u6); a2.x += t.x; a2.y += t.y; a2.z += t.z; a2.w += t.w;
        t = cvt4(u7); a3.x += t.x; a3.y += t.y; a3.z += t.z; a3.w += t.w;
    }
    for (; j + 3 < end; j += 4) {
        uint2 u0 = H2[(size_t)srcs[j + 0] * 32 + hl];
        uint2 u1 = H2[(size_t)srcs[j + 1] * 32 + hl];
        uint2 u2 = H2[(size_t)srcs[j + 2] * 32 + hl];
        uint2 u3 = H2[(size_t)srcs[j + 3] * 32 + hl];
        float4 t;
        t = cvt4(u0); a0.x += t.x; a0.y += t.y; a0.z += t.z; a0.w += t.w;
        t = cvt4(u1); a1.x += t.x; a1.y += t.y; a1.z += t.z; a1.w += t.w;
        t = cvt4(u2); a2.x += t.x; a2.y += t.y; a2.z += t.z; a2.w += t.w;
        t = cvt4(u3); a3.x += t.x; a3.y += t.y; a3.z += t.z; a3.w += t.w;
    }
    for (; j < end; ++j) {
        float4 t = cvt4(H2[(size_t)srcs[j] * 32 + hl]);
        a0.x += t.x; a0.y += t.y; a0.z += t.z; a0.w += t.w;
    }
    a0.x += a1.x + a2.x + a3.x;
    a0.y += a1.y + a2.y + a3.y;
    a0.z += a1.z + a2.z + a3.z;
    a0.w += a1.w + a2.w + a3.w;

    float di = dinv[n];
    float4 bv = ((const float4*)bias)[hl];
    float ox = di * a0.x + bv.x;
    float oy = di * a0.y + bv.y;
    float oz = di * a0.z + bv.z;
    float ow = di * a0.w + bv.w;
    if (do_relu) {
        ox = fmaxf(ox, 0.f); oy = fmaxf(oy, 0.f);
        oz = fmaxf(oz, 0.f); ow = fmaxf(ow, 0.f);
    }
    uint2 o;
    o.x = pack2(ox, oy);
    o.y = pack2(oz, ow);
    ((uint2*)Z)[(size_t)n * 32 + hl] = o;
}

// Decode: 4 pairs per half-wave -> 8 row-gathers in flight, 4 interleaved shfl chains,
// one float4 store per group. P must allow the tail path (guarded).
__global__ __launch_bounds__(256) void decode_kernel(const unsigned short* __restrict__ Z,
                                                     const int* __restrict__ pa,
                                                     const int* __restrict__ pb,
                                                     float* __restrict__ out, int P) {
    int grp = (int)((blockIdx.x * blockDim.x + threadIdx.x) >> 5);  // half-wave id
    int hl = threadIdx.x & 31;
    int p0 = grp * 4;
    if (p0 >= P) return;
    const uint2* Z2 = (const uint2*)Z;

    if (p0 + 3 < P) {
        int A0 = pa[p0], A1 = pa[p0 + 1], A2 = pa[p0 + 2], A3 = pa[p0 + 3];
        int B0 = pb[p0], B1 = pb[p0 + 1], B2 = pb[p0 + 2], B3 = pb[p0 + 3];
        uint2 ua0 = Z2[(size_t)A0 * 32 + hl];
        uint2 ub0 = Z2[(size_t)B0 * 32 + hl];
        uint2 ua1 = Z2[(size_t)A1 * 32 + hl];
        uint2 ub1 = Z2[(size_t)B1 * 32 + hl];
        uint2 ua2 = Z2[(size_t)A2 * 32 + hl];
        uint2 ub2 = Z2[(size_t)B2 * 32 + hl];
        uint2 ua3 = Z2[(size_t)A3 * 32 + hl];
        uint2 ub3 = Z2[(size_t)B3 * 32 + hl];
        float4 va, vb;
        va = cvt4(ua0); vb = cvt4(ub0);
        float v0 = va.x * vb.x + va.y * vb.y + va.z * vb.z + va.w * vb.w;
        va = cvt4(ua1); vb = cvt4(ub1);
        float v1 = va.x * vb.x + va.y * vb.y + va.z * vb.z + va.w * vb.w;
        va = cvt4(ua2); vb = cvt4(ub2);
        float v2 = va.x * vb.x + va.y * vb.y + va.z * vb.z + va.w * vb.w;
        va = cvt4(ua3); vb = cvt4(ub3);
        float v3 = va.x * vb.x + va.y * vb.y + va.z * vb.z + va.w * vb.w;
#pragma unroll
        for (int off = 16; off > 0; off >>= 1) {
            v0 += __shfl_down(v0, off, 32);
            v1 += __shfl_down(v1, off, 32);
            v2 += __shfl_down(v2, off, 32);
            v3 += __shfl_down(v3, off, 32);
        }
        if (hl == 0) *(float4*)&out[p0] = make_float4(v0, v1, v2, v3);
    } else {
        for (int p = p0; p < P; ++p) {
            float4 va = cvt4(Z2[(size_t)pa[p] * 32 + hl]);
            float4 vb = cvt4(Z2[(size_t)pb[p] * 32 + hl]);
            float v = va.x * vb.x + va.y * vb.y + va.z * vb.z + va.w * vb.w;
#pragma unroll
            for (int off = 16; off > 0; off >>= 1) v += __shfl_down(v, off, 32);
            if (hl == 0) out[p] = v;
        }
    }
}

extern "C" void kernel_launch(void* const* d_in, const int* in_sizes, int n_in,
                              void* d_out, int out_size, void* d_ws, size_t ws_size,
                              hipStream_t stream) {
    const int*   edge_index = (const int*)d_in[0];
    const int*   edge_pairs = (const int*)d_in[1];
    const float* emb        = (const float*)d_in[2];
    const float* W1         = (const float*)d_in[3];
    const float* b1         = (const float*)d_in[4];
    const float* W2         = (const float*)d_in[5];
    const float* b2         = (const float*)d_in[6];
    float* out = (float*)d_out;

    int E = in_sizes[0] / 2;
    int P = in_sizes[1] / 2;
    int N = in_sizes[2] / 128;
    int NB = (N + 63) / 64;    // buckets (782 for N=50000; must be <= 1024)

    const int* src = edge_index;
    const int* dst = edge_index + E;
    const int* pa  = edge_pairs;
    const int* pb  = edge_pairs + P;

    char* ws = (char*)d_ws;
    size_t off = 0;
    auto alloc = [&](size_t bytes) -> void* {
        void* p = ws + off;
        off = (off + bytes + 255) & ~(size_t)255;
        return p;
    };
    unsigned short* bufA = (unsigned short*)alloc((size_t)N * 128 * 2); // h' (bf16)
    unsigned short* bufB = (unsigned short*)alloc((size_t)N * 128 * 2); // z  (bf16)
    int*   srcs_sorted  = (int*)alloc((size_t)E * sizeof(int));
    unsigned int* stage = (unsigned int*)alloc((size_t)E * sizeof(unsigned int));
    int*   row_ptr      = (int*)alloc((size_t)(N + 1) * sizeof(int));
    float* dinv         = (float*)alloc((size_t)N * sizeof(float));
    int*   bhist        = (int*)alloc((size_t)STAGE_G * NB * sizeof(int));
    int*   T            = (int*)alloc((size_t)NB * sizeof(int));
    int*   bucket_base  = (int*)alloc((size_t)(NB + 1) * sizeof(int));

    // CSR build — no hot global atomics anywhere.
    block_hist_kernel<<<STAGE_G, 256, 0, stream>>>(dst, bhist, E, NB);
    s1_scan_blocks<<<NB, 128, 0, stream>>>(bhist, T, NB);
    s2_scan_buckets<<<1, 256, 0, stream>>>(T, bucket_base, NB);
    stage_kernel<<<STAGE_G, 256, 0, stream>>>(src, dst, bhist, bucket_base, stage, E, NB);
    scatter_kernel<<<NB, 256, 0, stream>>>(stage, bucket_base, row_ptr, dinv, srcs_sorted, N);

    // Layer 1: h1' = dinv*(emb@W1) -> agg+b1+relu -> z1 (bufB)
    gemm_mfma_kernel<false><<<(N + 63) / 64, 256, 0, stream>>>(emb, W1, dinv, (uint2*)bufA, N);
    agg_kernel<<<(N + 7) / 8, 256, 0, stream>>>(bufA, row_ptr, srcs_sorted, dinv, b1, bufB, N, 1);

    // Layer 2: h2' = dinv*(z1@W2) -> agg+b2 -> z2 (bufB)
    gemm_mfma_kernel<true><<<(N + 63) / 64, 256, 0, stream>>>(bufB, W2, dinv, (uint2*)bufA, N);
    agg_kernel<<<(N + 7) / 8, 256, 0, stream>>>(bufA, row_ptr, srcs_sorted, dinv, b2, bufB, N, 0);

    // Decode: 4 pairs/half-wave -> 32 pairs/block
    decode_kernel<<<(P + 31) / 32, 256, 0, stream>>>(bufB, pa, pb, out, P);
}